// Round 1
// baseline (144.864 us; speedup 1.0000x reference)
//
#include <hip/hip_runtime.h>
#include <math.h>

#define BB 16
#define PP 4096
#define TT 1024

// One block per (b, t) target: find argmin-distance valid pred, mark it.
__global__ __launch_bounds__(256) void match_kernel(const float* __restrict__ pred,
                                                    const float* __restrict__ gt,
                                                    int* __restrict__ hits) {
    const int bt = blockIdx.x;
    const int b = bt >> 10;          // / TT
    const int t = bt & (TT - 1);     // % TT
    const float* g = gt + (size_t)(b * TT + t) * 3;
    const float gcls = g[0];
    const float gx   = g[1];
    const float gy   = g[2];
    const float* pb = pred + (size_t)b * PP * 3;

    float bestD = INFINITY;
    int   bestP = 0x7fffffff;

    for (int p = threadIdx.x; p < PP; p += 256) {
        const float pcls = pb[p * 3 + 0];
        const float px   = pb[p * 3 + 1];
        const float py   = pb[p * 3 + 2];
        const float dx = px - gx;
        const float dy = py - gy;
        const float d2 = dx * dx + dy * dy;
        const float dist = sqrtf(d2);
        // reference: sigmoid(1 - dist/5) >= 0.5  <=>  1 - dist/5 >= 0
        const bool valid = (pcls == gcls) && (1.0f - dist / 5.0f >= 0.0f);
        if (valid) {
            if (dist < bestD) { bestD = dist; bestP = p; }
            // equal dist with larger p cannot replace (p increases in-loop)
        }
    }

    // wave (64-lane) reduction: min dist, tie-break lowest p
    for (int off = 32; off; off >>= 1) {
        const float od = __shfl_down(bestD, off, 64);
        const int   op = __shfl_down(bestP, off, 64);
        if (od < bestD || (od == bestD && op < bestP)) { bestD = od; bestP = op; }
    }

    __shared__ float sd[4];
    __shared__ int   sp[4];
    const int wid  = threadIdx.x >> 6;
    const int lane = threadIdx.x & 63;
    if (lane == 0) { sd[wid] = bestD; sp[wid] = bestP; }
    __syncthreads();
    if (threadIdx.x == 0) {
        for (int w = 1; w < 4; ++w) {
            if (sd[w] < bestD || (sd[w] == bestD && sp[w] < bestP)) { bestD = sd[w]; bestP = sp[w]; }
        }
        if (bestP != 0x7fffffff) {
            hits[b * PP + bestP] = 1;   // benign same-value race across blocks
        }
    }
}

// Single block: sum hits -> tp, compute F1 loss scalar.
__global__ __launch_bounds__(1024) void count_kernel(const int* __restrict__ hits,
                                                     float* __restrict__ out) {
    int sum = 0;
    for (int i = threadIdx.x; i < BB * PP; i += 1024) sum += hits[i];
    for (int off = 32; off; off >>= 1) sum += __shfl_down(sum, off, 64);

    __shared__ int ss[16];
    const int wid  = threadIdx.x >> 6;
    const int lane = threadIdx.x & 63;
    if (lane == 0) ss[wid] = sum;
    __syncthreads();
    if (threadIdx.x == 0) {
        int tp_i = 0;
        for (int w = 0; w < 16; ++w) tp_i += ss[w];
        const float tp = (float)tp_i;
        const float eps = 1e-6f;
        const float fp = (float)(BB * PP) - tp;
        const float fn = (float)(BB * TT) - tp;
        const float precision = (tp + eps) / (tp + eps + fp + eps);
        const float recall    = (tp + eps) / (tp + fn + eps);
        const float f1 = 2.0f * precision * recall / (precision + recall);
        out[0] = 1.0f - f1;
    }
}

extern "C" void kernel_launch(void* const* d_in, const int* in_sizes, int n_in,
                              void* d_out, int out_size, void* d_ws, size_t ws_size,
                              hipStream_t stream) {
    const float* pred = (const float*)d_in[0];  // (B, P, 3): cls, x, y
    const float* gt   = (const float*)d_in[1];  // (B, T, 3)
    float* out = (float*)d_out;
    int* hits = (int*)d_ws;                     // B*P ints = 256 KB

    hipMemsetAsync(hits, 0, (size_t)BB * PP * sizeof(int), stream);
    match_kernel<<<BB * TT, 256, 0, stream>>>(pred, gt, hits);
    count_kernel<<<1, 1024, 0, stream>>>(hits, out);
}

// Round 2
// 79.151 us; speedup vs baseline: 1.8302x; 1.8302x over previous
//
#include <hip/hip_runtime.h>
#include <math.h>

#define BB 16
#define PP 4096
#define TT 1024
#define SENT 0xFFFFFFFFu

// Grid: 1024 blocks = 16 b x 64 target-tiles. Block = 256 thr = 4 waves.
// Each wave owns 4 targets and scans ALL P preds (lane = p mod 64, 64 preds/lane).
// Final per-target argmin via packed (d2,p) u64 wave shuffle-min -> lowest-p tie-break.
__global__ __launch_bounds__(256) void match_kernel(const float* __restrict__ pred,
                                                    const float* __restrict__ gt,
                                                    unsigned char* __restrict__ hits) {
    const int blk   = blockIdx.x;
    const int b     = blk >> 6;          // 64 blocks per batch
    const int ttile = blk & 63;          // 16 targets per block
    const int wave  = threadIdx.x >> 6;  // 0..3
    const int lane  = threadIdx.x & 63;
    const int tbase = ttile * 16 + wave * 4;

    const float* gb = gt + ((size_t)(b * TT + tbase)) * 3;
    float gc[4], gx[4], gy[4], bd[4];
    unsigned int bp[4];
    #pragma unroll
    for (int j = 0; j < 4; ++j) {
        gc[j] = gb[j * 3 + 0];
        gx[j] = gb[j * 3 + 1];
        gy[j] = gb[j * 3 + 2];
        bd[j] = INFINITY;
        bp[j] = SENT;
    }

    const float* pb = pred + (size_t)b * PP * 3;

    #pragma unroll 4
    for (int i = 0; i < PP / 64; ++i) {
        const int p = lane + (i << 6);
        const float pc = pb[p * 3 + 0];
        const float px = pb[p * 3 + 1];
        const float py = pb[p * 3 + 2];
        #pragma unroll
        for (int j = 0; j < 4; ++j) {
            const float dx = px - gx[j];
            const float dy = py - gy[j];
            const float d2 = dx * dx + dy * dy;
            // valid: class match AND dist<=5 (d2<=25); strict < keeps lowest p in-lane
            const bool ok = (pc == gc[j]) & (d2 <= 25.0f) & (d2 < bd[j]);
            if (ok) { bd[j] = d2; bp[j] = (unsigned int)p; }
        }
    }

    // pack: d2 >= 0 so float bits order == uint order; lower p wins ties
    unsigned long long key[4];
    #pragma unroll
    for (int j = 0; j < 4; ++j)
        key[j] = ((unsigned long long)__float_as_uint(bd[j]) << 32) | bp[j];

    for (int off = 32; off; off >>= 1) {
        #pragma unroll
        for (int j = 0; j < 4; ++j) {
            const unsigned long long o = __shfl_down(key[j], off, 64);
            if (o < key[j]) key[j] = o;
        }
    }

    if (lane == 0) {
        #pragma unroll
        for (int j = 0; j < 4; ++j) {
            const unsigned int p = (unsigned int)key[j];
            if (p != SENT) hits[b * PP + p] = 1;  // benign same-value race
        }
    }
}

// Single block: sum 64K hit bytes -> tp, compute F1 loss scalar.
__global__ __launch_bounds__(1024) void count_kernel(const unsigned int* __restrict__ hits,
                                                     float* __restrict__ out) {
    int sum = 0;
    // 65536 bytes = 16384 u32 words; 1024 threads x 16 words (4x uint4)
    for (int i = threadIdx.x; i < (BB * PP / 4); i += 1024) {
        unsigned int v = hits[i];                      // 4 bytes, each 0/1
        unsigned int t = (v & 0x00FF00FFu) + ((v >> 8) & 0x00FF00FFu);
        sum += (int)((t & 0xFFFFu) + (t >> 16));
    }
    for (int off = 32; off; off >>= 1) sum += __shfl_down(sum, off, 64);

    __shared__ int ss[16];
    const int wid  = threadIdx.x >> 6;
    const int lane = threadIdx.x & 63;
    if (lane == 0) ss[wid] = sum;
    __syncthreads();
    if (threadIdx.x == 0) {
        int tp_i = 0;
        for (int w = 0; w < 16; ++w) tp_i += ss[w];
        const float tp = (float)tp_i;
        const float eps = 1e-6f;
        const float fp = (float)(BB * PP) - tp;
        const float fn = (float)(BB * TT) - tp;
        const float precision = (tp + eps) / (tp + eps + fp + eps);
        const float recall    = (tp + eps) / (tp + fn + eps);
        const float f1 = 2.0f * precision * recall / (precision + recall);
        out[0] = 1.0f - f1;
    }
}

extern "C" void kernel_launch(void* const* d_in, const int* in_sizes, int n_in,
                              void* d_out, int out_size, void* d_ws, size_t ws_size,
                              hipStream_t stream) {
    const float* pred = (const float*)d_in[0];  // (B, P, 3): cls, x, y
    const float* gt   = (const float*)d_in[1];  // (B, T, 3)
    float* out = (float*)d_out;
    unsigned char* hits = (unsigned char*)d_ws; // B*P bytes = 64 KB

    hipMemsetAsync(hits, 0, (size_t)BB * PP, stream);
    match_kernel<<<BB * TT / 16, 256, 0, stream>>>(pred, gt, hits);
    count_kernel<<<1, 1024, 0, stream>>>((const unsigned int*)hits, out);
}